// Round 18
// baseline (172.248 us; speedup 1.0000x reference)
//
#include <hip/hip_runtime.h>
#include <hip/hip_bf16.h>

typedef __attribute__((ext_vector_type(8))) short bf16x8;
typedef __attribute__((ext_vector_type(4))) float f32x4;
typedef __attribute__((ext_vector_type(4))) unsigned short ushort4v;
typedef __attribute__((ext_vector_type(2))) unsigned uint2v;

__device__ __forceinline__ unsigned short f2bf(float f) {
  union { float f; unsigned u; } v; v.f = f;
  unsigned r = v.u + 0x7FFFu + ((v.u >> 16) & 1u);
  return (unsigned short)(r >> 16);
}

__device__ __forceinline__ unsigned pack_bf2(float lo, float hi) {
  __hip_bfloat162 h = __float22bfloat162_rn(make_float2(lo, hi));
  union { __hip_bfloat162 h; unsigned u; } cv; cv.h = h; return cv.u;
}

__device__ __forceinline__ void gll16(const void* g, void* l) {
  __builtin_amdgcn_global_load_lds((const __attribute__((address_space(1))) void*)g,
                                   (__attribute__((address_space(3))) void*)l, 16, 0, 0);
}

#define MFMA16(a, b, c) __builtin_amdgcn_mfma_f32_16x16x32_bf16((a), (b), (c), 0, 0, 0)

// ---------------------------------------------------------------- fused convert (grid-stride)
__global__ void cvt3(const float* __restrict__ x, const float* __restrict__ wq,
                     const float* __restrict__ wp,
                     unsigned short* __restrict__ xb, unsigned short* __restrict__ wqb,
                     unsigned short* __restrict__ wpb) {
  const int total = 3145728;                 // 12582912 elems / 4
  for (int v = blockIdx.x * blockDim.x + threadIdx.x; v < total; v += gridDim.x * blockDim.x) {
    int i = v * 4;
    const float* s; unsigned short* d;
    if (i < 8388608)        { s = x  + i;              d = xb  + i; }
    else if (i < 11534336)  { s = wq + (i - 8388608);  d = wqb + (i - 8388608); }
    else                    { s = wp + (i - 11534336); d = wpb + (i - 11534336); }
    float4 f = *(const float4*)s;
    ushort4v r;
    r[0] = f2bf(f.x); r[1] = f2bf(f.y); r[2] = f2bf(f.z); r[3] = f2bf(f.w);
    *(ushort4v*)d = r;
  }
}

// ---------------------------------------------------------------- GEMM NT, BK=32 (r13, frozen)
template<int EPI, int MIF>
__global__ __launch_bounds__(256, 2)
void gemmf(const unsigned short* __restrict__ A,
           const unsigned short* __restrict__ B,
           unsigned short* __restrict__ obf,
           float* __restrict__ of32,
           int M, int N, int K) {
  extern __shared__ char lds[];
  constexpr int BM = MIF * 32;
  constexpr int BUFB = (BM + 128) * 64;
  const int tid = threadIdx.x, wid = tid >> 6, lane = tid & 63;
  const int c = lane & 15, g = lane >> 4;
  const int wm = wid >> 1, wn = wid & 1;
  const int nbn = N >> 7;
  const int wg = (blockIdx.x & 7) * (gridDim.x >> 3) + (blockIdx.x >> 3);
  const int m0 = (wg / nbn) * BM, n0 = (wg % nbn) * 128;
  const int NT = K >> 5;
  const size_t rb = (size_t)K * 2;
  const int rk = (c ^ (c >> 2)) & 3;

  const int lrow = lane >> 2;
  const int lslot = (lane & 3) ^ (((lane >> 2) ^ (lane >> 4)) & 3);
  const char* Ab = (const char*)A + (size_t)m0 * rb + (size_t)lrow * rb + lslot * 16;
  const char* Bb = (const char*)B + (size_t)n0 * rb + (size_t)lrow * rb + lslot * 16;

  auto stage = [&](int t, int buf) {
    char* base = lds + buf * BUFB;
#pragma unroll
    for (int j = 0; j < MIF / 2; ++j) {
      int ch = wid * (MIF / 2) + j;
      gll16(Ab + (size_t)(ch * 16) * rb + t * 64, base + ch * 1024);
    }
#pragma unroll
    for (int j = 0; j < 2; ++j) {
      int ch = wid * 2 + j;
      gll16(Bb + (size_t)(ch * 16) * rb + t * 64, base + BM * 64 + ch * 1024);
    }
  };

  f32x4 acc[MIF][4];
#pragma unroll
  for (int i = 0; i < MIF; ++i)
#pragma unroll
    for (int j = 0; j < 4; ++j) acc[i][j] = f32x4{0.f, 0.f, 0.f, 0.f};

  stage(0, 0); stage(1, 1);
  if constexpr (MIF == 8) { asm volatile("s_waitcnt vmcnt(6)" ::: "memory"); }
  else                    { asm volatile("s_waitcnt vmcnt(4)" ::: "memory"); }
  __builtin_amdgcn_s_barrier();

  const int col = ((g ^ rk) << 4);
  for (int t = 0; t < NT; ++t) {
    const char* base = lds + (t % 3) * BUFB;
    bf16x8 af[MIF], bfr[4];
#pragma unroll
    for (int mi = 0; mi < MIF; ++mi) {
      int arow = wm * (MIF * 16) + mi * 16 + c;
      af[mi] = *(const bf16x8*)(base + arow * 64 + col);
    }
#pragma unroll
    for (int ni = 0; ni < 4; ++ni) {
      int brow = wn * 64 + ni * 16 + c;
      bfr[ni] = *(const bf16x8*)(base + BM * 64 + brow * 64 + col);
    }
    const bool more = (t + 2 < NT);
    if (more) stage(t + 2, (t + 2) % 3);
    asm volatile("s_waitcnt lgkmcnt(0)" ::: "memory");
    __builtin_amdgcn_sched_barrier(0);
    __builtin_amdgcn_s_setprio(1);
#pragma unroll
    for (int mi = 0; mi < MIF; ++mi)
#pragma unroll
      for (int ni = 0; ni < 4; ++ni)
        acc[mi][ni] = MFMA16(bfr[ni], af[mi], acc[mi][ni]);   // swapped: acc = C^T
    __builtin_amdgcn_s_setprio(0);
    if (more) {
      if constexpr (MIF == 8) { asm volatile("s_waitcnt vmcnt(6)" ::: "memory"); }
      else                    { asm volatile("s_waitcnt vmcnt(4)" ::: "memory"); }
    } else {
      asm volatile("s_waitcnt vmcnt(0)" ::: "memory");
    }
    __builtin_amdgcn_s_barrier();
  }

#pragma unroll
  for (int mi = 0; mi < MIF; ++mi) {
    int mg = m0 + wm * (MIF * 16) + mi * 16 + c;
    if (EPI == 0) {
      int bb = mg >> 11, tt = mg & 2047;
      size_t rowbase = ((size_t)(bb * 16) * 2048 + tt) * 64;
#pragma unroll
      for (int ni = 0; ni < 4; ++ni) {
        int ng = n0 + wn * 64 + ni * 16 + g * 4;
        int which = ng >> 10, rem = ng & 1023;
        int hh = rem >> 6, dd = rem & 63;
        uint2v pk;
        pk[0] = pack_bf2(acc[mi][ni][0], acc[mi][ni][1]);
        pk[1] = pack_bf2(acc[mi][ni][2], acc[mi][ni][3]);
        *(uint2v*)(obf + (size_t)which * 8388608u + rowbase + (size_t)hh * 131072 + dd) = pk;
      }
    } else {
      float* orow = of32 + (size_t)mg * N + n0 + wn * 64 + g * 4;
#pragma unroll
      for (int ni = 0; ni < 4; ++ni)
        *(f32x4*)(orow + ni * 16) = acc[mi][ni];
    }
  }
}

// ---------------------------------------------------------------- flash attention (r10 + setprio ONLY; pad stays 72)
__global__ __launch_bounds__(256, 6)
void attn_fwd(const unsigned short* __restrict__ qb,
              const unsigned short* __restrict__ kb,
              const unsigned short* __restrict__ vb,
              unsigned short* __restrict__ yb) {
  __shared__ unsigned short Kt[64 * 64];
  __shared__ unsigned short Vt[64 * 64];
  __shared__ unsigned short Pl[4 * 16 * 72];
  const int tid = threadIdx.x, w = tid >> 6, lane = tid & 63;
  const int c = lane & 15, g = lane >> 4;
  const int bh = blockIdx.x & 63;
  const int qt = 31 - (blockIdx.x >> 6);
  const int q0 = qt * 64;
  const int b = bh >> 4, h = bh & 15;
  const size_t hb = (size_t)bh * 131072;
  const float GAM = 0.125f * 1.44269504089f;

  const unsigned short* qp = qb + hb + (size_t)(q0 + w * 16 + c) * 64;
  bf16x8 qf0 = *(const bf16x8*)(qp + g * 8);
  bf16x8 qf1 = *(const bf16x8*)(qp + 32 + g * 8);

  f32x4 yacc[4];
#pragma unroll
  for (int i = 0; i < 4; ++i) yacc[i] = f32x4{0.f, 0.f, 0.f, 0.f};
  float mrun = -1e30f, lsum = 0.f;
  unsigned short* pw = Pl + w * (16 * 72);

  for (int kv = 0; kv <= qt; ++kv) {
    const int kv0 = kv * 64;
    const bool diag = (kv == qt);
    if (kv) __syncthreads();
#pragma unroll
    for (int r = 0; r < 2; ++r) {
      int chunk = w * 2 + r;
      int row = chunk * 8 + (lane >> 3);
      int bo = (lane & 7) * 16;
      int sbo = bo ^ ((row & 7) << 4);
      gll16((const char*)(kb + hb + (size_t)(kv0 + row) * 64) + sbo, Kt + chunk * 512);
    }
    {
      int kv2 = (lane & 31) * 2;
      int dblk = w * 16 + (lane >> 5) * 8;
      const unsigned short* vp = vb + hb + (size_t)(kv0 + kv2) * 64 + dblk;
      bf16x8 r0 = *(const bf16x8*)(vp);
      bf16x8 r1 = *(const bf16x8*)(vp + 64);
#pragma unroll
      for (int i = 0; i < 8; ++i) {
        int d = dblk + i;
        unsigned pk2 = ((unsigned)(unsigned short)r0[i]) | (((unsigned)(unsigned short)r1[i]) << 16);
        *(unsigned*)(Vt + d * 64 + (kv2 ^ ((d & 7) << 3))) = pk2;
      }
    }
    __syncthreads();

    f32x4 sacc[4];
#pragma unroll
    for (int nt = 0; nt < 4; ++nt) sacc[nt] = f32x4{0.f, 0.f, 0.f, 0.f};
    __builtin_amdgcn_s_setprio(1);
#pragma unroll
    for (int kk = 0; kk < 2; ++kk)
#pragma unroll
      for (int nt = 0; nt < 4; ++nt) {
        int row = nt * 16 + c;
        bf16x8 kf = *(const bf16x8*)(Kt + row * 64 + ((kk * 32 + g * 8) ^ ((row & 7) << 3)));
        sacc[nt] = MFMA16(kf, (kk ? qf1 : qf0), sacc[nt]);
      }
    __builtin_amdgcn_s_setprio(0);

    if (diag) {
      int ql = w * 16 + c;
#pragma unroll
      for (int nt = 0; nt < 4; ++nt)
#pragma unroll
        for (int r = 0; r < 4; ++r)
          if (nt * 16 + g * 4 + r > ql) sacc[nt][r] = -1e30f;
    }

    float m0 = -1e30f;
#pragma unroll
    for (int nt = 0; nt < 4; ++nt) {
      float a = fmaxf(fmaxf(sacc[nt][0], sacc[nt][1]), fmaxf(sacc[nt][2], sacc[nt][3]));
      m0 = fmaxf(m0, a);
    }
    m0 = fmaxf(m0, __shfl_xor(m0, 16));
    m0 = fmaxf(m0, __shfl_xor(m0, 32));

    if (__any(m0 > mrun + 32.0f)) {
      float mnew = fmaxf(mrun, m0);
      float corr = __builtin_amdgcn_exp2f(GAM * (mrun - mnew));
      lsum *= corr;
#pragma unroll
      for (int dt = 0; dt < 4; ++dt) yacc[dt] *= corr;
      mrun = mnew;
    }

    float bexp = -GAM * mrun;
    float psum = 0.f;
#pragma unroll
    for (int nt = 0; nt < 4; ++nt) {
      float p0 = __builtin_amdgcn_exp2f(fmaf(sacc[nt][0], GAM, bexp));
      float p1 = __builtin_amdgcn_exp2f(fmaf(sacc[nt][1], GAM, bexp));
      float p2 = __builtin_amdgcn_exp2f(fmaf(sacc[nt][2], GAM, bexp));
      float p3 = __builtin_amdgcn_exp2f(fmaf(sacc[nt][3], GAM, bexp));
      psum += (p0 + p1) + (p2 + p3);
      uint2v pkv;
      pkv[0] = pack_bf2(p0, p1);
      pkv[1] = pack_bf2(p2, p3);
      *(uint2v*)(pw + c * 72 + nt * 16 + g * 4) = pkv;
    }
    lsum += psum;

    __builtin_amdgcn_s_setprio(1);
#pragma unroll
    for (int kk = 0; kk < 2; ++kk) {
      bf16x8 pb = *(const bf16x8*)(pw + c * 72 + kk * 32 + g * 8);
#pragma unroll
      for (int dt = 0; dt < 4; ++dt) {
        int n = dt * 16 + c;
        bf16x8 vf = *(const bf16x8*)(Vt + n * 64 + ((kk * 32 + g * 8) ^ ((n & 7) << 3)));
        yacc[dt] = MFMA16(vf, pb, yacc[dt]);
      }
    }
    __builtin_amdgcn_s_setprio(0);
  }

  lsum += __shfl_xor(lsum, 16);
  lsum += __shfl_xor(lsum, 32);
  float inv = 1.0f / lsum;
  int row = q0 + w * 16 + c;
  unsigned short* yp = yb + ((size_t)(b * 2048 + row)) * 1024 + h * 64;
#pragma unroll
  for (int dt = 0; dt < 4; ++dt) {
    uint2v pkv;
    pkv[0] = pack_bf2(yacc[dt][0] * inv, yacc[dt][1] * inv);
    pkv[1] = pack_bf2(yacc[dt][2] * inv, yacc[dt][3] * inv);
    *(uint2v*)(yp + dt * 16 + g * 4) = pkv;
  }
}

// ---------------------------------------------------------------- launch
extern "C" void kernel_launch(void* const* d_in, const int* in_sizes, int n_in,
                              void* d_out, int out_size, void* d_ws, size_t ws_size,
                              hipStream_t stream) {
  const float* x     = (const float*)d_in[0];
  const float* wqkv  = (const float*)d_in[1];
  const float* wproj = (const float*)d_in[2];
  float* out = (float*)d_out;

  unsigned short* ws     = (unsigned short*)d_ws;
  unsigned short* xb     = ws;                       // 8388608
  unsigned short* wqkvb  = xb + 8388608;             // 3145728
  unsigned short* wprojb = wqkvb + 3145728;          // 1048576
  unsigned short* qkvb   = wprojb + 1048576;         // 3 * 8388608 (q,k,v)
  unsigned short* yb     = qkvb + 3 * 8388608;       // 8388608

  cvt3<<<2048, 256, 0, stream>>>(x, wqkv, wproj, xb, wqkvb, wprojb);

  // gemm1: BM=256 BN=128 BK=32, 3-ring 72KB LDS, grid 768
  gemmf<0, 8><<<768, 256, 73728, stream>>>(xb, wqkvb, qkvb, nullptr, 8192, 3072, 1024);
  attn_fwd<<<2048, 256, 0, stream>>>(qkvb, qkvb + 8388608, qkvb + 2 * 8388608, yb);
  // gemm2: BM=128 BN=128, 48KB LDS, grid 512
  gemmf<1, 4><<<512, 256, 49152, stream>>>(yb, wprojb, nullptr, out, 8192, 1024, 1024);
}

// Round 19
// 171.040 us; speedup vs baseline: 1.0071x; 1.0071x over previous
//
#include <hip/hip_runtime.h>
#include <hip/hip_bf16.h>

typedef __attribute__((ext_vector_type(8))) short bf16x8;
typedef __attribute__((ext_vector_type(4))) float f32x4;
typedef __attribute__((ext_vector_type(4))) unsigned short ushort4v;
typedef __attribute__((ext_vector_type(2))) unsigned uint2v;

__device__ __forceinline__ unsigned short f2bf(float f) {
  union { float f; unsigned u; } v; v.f = f;
  unsigned r = v.u + 0x7FFFu + ((v.u >> 16) & 1u);
  return (unsigned short)(r >> 16);
}

__device__ __forceinline__ unsigned pack_bf2(float lo, float hi) {
  __hip_bfloat162 h = __float22bfloat162_rn(make_float2(lo, hi));
  union { __hip_bfloat162 h; unsigned u; } cv; cv.h = h; return cv.u;
}

__device__ __forceinline__ void gll16(const void* g, void* l) {
  __builtin_amdgcn_global_load_lds((const __attribute__((address_space(1))) void*)g,
                                   (__attribute__((address_space(3))) void*)l, 16, 0, 0);
}

#define MFMA16(a, b, c) __builtin_amdgcn_mfma_f32_16x16x32_bf16((a), (b), (c), 0, 0, 0)

// ---------------------------------------------------------------- fused convert (grid-stride)
__global__ void cvt3(const float* __restrict__ x, const float* __restrict__ wq,
                     const float* __restrict__ wp,
                     unsigned short* __restrict__ xb, unsigned short* __restrict__ wqb,
                     unsigned short* __restrict__ wpb) {
  const int total = 3145728;                 // 12582912 elems / 4
  for (int v = blockIdx.x * blockDim.x + threadIdx.x; v < total; v += gridDim.x * blockDim.x) {
    int i = v * 4;
    const float* s; unsigned short* d;
    if (i < 8388608)        { s = x  + i;              d = xb  + i; }
    else if (i < 11534336)  { s = wq + (i - 8388608);  d = wqb + (i - 8388608); }
    else                    { s = wp + (i - 11534336); d = wpb + (i - 11534336); }
    float4 f = *(const float4*)s;
    ushort4v r;
    r[0] = f2bf(f.x); r[1] = f2bf(f.y); r[2] = f2bf(f.z); r[3] = f2bf(f.w);
    *(ushort4v*)d = r;
  }
}

// ---------------------------------------------------------------- GEMM NT, BK=32 (r13, frozen)
template<int EPI, int MIF>
__global__ __launch_bounds__(256, 2)
void gemmf(const unsigned short* __restrict__ A,
           const unsigned short* __restrict__ B,
           unsigned short* __restrict__ obf,
           float* __restrict__ of32,
           int M, int N, int K) {
  extern __shared__ char lds[];
  constexpr int BM = MIF * 32;
  constexpr int BUFB = (BM + 128) * 64;
  const int tid = threadIdx.x, wid = tid >> 6, lane = tid & 63;
  const int c = lane & 15, g = lane >> 4;
  const int wm = wid >> 1, wn = wid & 1;
  const int nbn = N >> 7;
  const int wg = (blockIdx.x & 7) * (gridDim.x >> 3) + (blockIdx.x >> 3);
  const int m0 = (wg / nbn) * BM, n0 = (wg % nbn) * 128;
  const int NT = K >> 5;
  const size_t rb = (size_t)K * 2;
  const int rk = (c ^ (c >> 2)) & 3;

  const int lrow = lane >> 2;
  const int lslot = (lane & 3) ^ (((lane >> 2) ^ (lane >> 4)) & 3);
  const char* Ab = (const char*)A + (size_t)m0 * rb + (size_t)lrow * rb + lslot * 16;
  const char* Bb = (const char*)B + (size_t)n0 * rb + (size_t)lrow * rb + lslot * 16;

  auto stage = [&](int t, int buf) {
    char* base = lds + buf * BUFB;
#pragma unroll
    for (int j = 0; j < MIF / 2; ++j) {
      int ch = wid * (MIF / 2) + j;
      gll16(Ab + (size_t)(ch * 16) * rb + t * 64, base + ch * 1024);
    }
#pragma unroll
    for (int j = 0; j < 2; ++j) {
      int ch = wid * 2 + j;
      gll16(Bb + (size_t)(ch * 16) * rb + t * 64, base + BM * 64 + ch * 1024);
    }
  };

  f32x4 acc[MIF][4];
#pragma unroll
  for (int i = 0; i < MIF; ++i)
#pragma unroll
    for (int j = 0; j < 4; ++j) acc[i][j] = f32x4{0.f, 0.f, 0.f, 0.f};

  stage(0, 0); stage(1, 1);
  if constexpr (MIF == 8) { asm volatile("s_waitcnt vmcnt(6)" ::: "memory"); }
  else                    { asm volatile("s_waitcnt vmcnt(4)" ::: "memory"); }
  __builtin_amdgcn_s_barrier();

  const int col = ((g ^ rk) << 4);
  for (int t = 0; t < NT; ++t) {
    const char* base = lds + (t % 3) * BUFB;
    bf16x8 af[MIF], bfr[4];
#pragma unroll
    for (int mi = 0; mi < MIF; ++mi) {
      int arow = wm * (MIF * 16) + mi * 16 + c;
      af[mi] = *(const bf16x8*)(base + arow * 64 + col);
    }
#pragma unroll
    for (int ni = 0; ni < 4; ++ni) {
      int brow = wn * 64 + ni * 16 + c;
      bfr[ni] = *(const bf16x8*)(base + BM * 64 + brow * 64 + col);
    }
    const bool more = (t + 2 < NT);
    if (more) stage(t + 2, (t + 2) % 3);
    asm volatile("s_waitcnt lgkmcnt(0)" ::: "memory");
    __builtin_amdgcn_sched_barrier(0);
    __builtin_amdgcn_s_setprio(1);
#pragma unroll
    for (int mi = 0; mi < MIF; ++mi)
#pragma unroll
      for (int ni = 0; ni < 4; ++ni)
        acc[mi][ni] = MFMA16(bfr[ni], af[mi], acc[mi][ni]);   // swapped: acc = C^T
    __builtin_amdgcn_s_setprio(0);
    if (more) {
      if constexpr (MIF == 8) { asm volatile("s_waitcnt vmcnt(6)" ::: "memory"); }
      else                    { asm volatile("s_waitcnt vmcnt(4)" ::: "memory"); }
    } else {
      asm volatile("s_waitcnt vmcnt(0)" ::: "memory");
    }
    __builtin_amdgcn_s_barrier();
  }

#pragma unroll
  for (int mi = 0; mi < MIF; ++mi) {
    int mg = m0 + wm * (MIF * 16) + mi * 16 + c;
    if (EPI == 0) {
      int bb = mg >> 11, tt = mg & 2047;
      size_t rowbase = ((size_t)(bb * 16) * 2048 + tt) * 64;
#pragma unroll
      for (int ni = 0; ni < 4; ++ni) {
        int ng = n0 + wn * 64 + ni * 16 + g * 4;
        int which = ng >> 10, rem = ng & 1023;
        int hh = rem >> 6, dd = rem & 63;
        uint2v pk;
        pk[0] = pack_bf2(acc[mi][ni][0], acc[mi][ni][1]);
        pk[1] = pack_bf2(acc[mi][ni][2], acc[mi][ni][3]);
        *(uint2v*)(obf + (size_t)which * 8388608u + rowbase + (size_t)hh * 131072 + dd) = pk;
      }
    } else {
      float* orow = of32 + (size_t)mg * N + n0 + wn * 64 + g * 4;
#pragma unroll
      for (int ni = 0; ni < 4; ++ni)
        *(f32x4*)(orow + ni * 16) = acc[mi][ni];
    }
  }
}

// ---------------------------------------------------------------- flash attention (r10 exact, known-good 77us)
__global__ __launch_bounds__(256, 6)
void attn_fwd(const unsigned short* __restrict__ qb,
              const unsigned short* __restrict__ kb,
              const unsigned short* __restrict__ vb,
              unsigned short* __restrict__ yb) {
  __shared__ unsigned short Kt[64 * 64];
  __shared__ unsigned short Vt[64 * 64];
  __shared__ unsigned short Pl[4 * 16 * 72];
  const int tid = threadIdx.x, w = tid >> 6, lane = tid & 63;
  const int c = lane & 15, g = lane >> 4;
  const int bh = blockIdx.x & 63;
  const int qt = 31 - (blockIdx.x >> 6);
  const int q0 = qt * 64;
  const int b = bh >> 4, h = bh & 15;
  const size_t hb = (size_t)bh * 131072;
  const float GAM = 0.125f * 1.44269504089f;

  const unsigned short* qp = qb + hb + (size_t)(q0 + w * 16 + c) * 64;
  bf16x8 qf0 = *(const bf16x8*)(qp + g * 8);
  bf16x8 qf1 = *(const bf16x8*)(qp + 32 + g * 8);

  f32x4 yacc[4];
#pragma unroll
  for (int i = 0; i < 4; ++i) yacc[i] = f32x4{0.f, 0.f, 0.f, 0.f};
  float mrun = -1e30f, lsum = 0.f;
  unsigned short* pw = Pl + w * (16 * 72);

  for (int kv = 0; kv <= qt; ++kv) {
    const int kv0 = kv * 64;
    const bool diag = (kv == qt);
    if (kv) __syncthreads();
#pragma unroll
    for (int r = 0; r < 2; ++r) {
      int chunk = w * 2 + r;
      int row = chunk * 8 + (lane >> 3);
      int bo = (lane & 7) * 16;
      int sbo = bo ^ ((row & 7) << 4);
      gll16((const char*)(kb + hb + (size_t)(kv0 + row) * 64) + sbo, Kt + chunk * 512);
    }
    {
      int kv2 = (lane & 31) * 2;
      int dblk = w * 16 + (lane >> 5) * 8;
      const unsigned short* vp = vb + hb + (size_t)(kv0 + kv2) * 64 + dblk;
      bf16x8 r0 = *(const bf16x8*)(vp);
      bf16x8 r1 = *(const bf16x8*)(vp + 64);
#pragma unroll
      for (int i = 0; i < 8; ++i) {
        int d = dblk + i;
        unsigned pk2 = ((unsigned)(unsigned short)r0[i]) | (((unsigned)(unsigned short)r1[i]) << 16);
        *(unsigned*)(Vt + d * 64 + (kv2 ^ ((d & 7) << 3))) = pk2;
      }
    }
    __syncthreads();

    f32x4 sacc[4];
#pragma unroll
    for (int nt = 0; nt < 4; ++nt) sacc[nt] = f32x4{0.f, 0.f, 0.f, 0.f};
#pragma unroll
    for (int kk = 0; kk < 2; ++kk)
#pragma unroll
      for (int nt = 0; nt < 4; ++nt) {
        int row = nt * 16 + c;
        bf16x8 kf = *(const bf16x8*)(Kt + row * 64 + ((kk * 32 + g * 8) ^ ((row & 7) << 3)));
        sacc[nt] = MFMA16(kf, (kk ? qf1 : qf0), sacc[nt]);
      }

    if (diag) {
      int ql = w * 16 + c;
#pragma unroll
      for (int nt = 0; nt < 4; ++nt)
#pragma unroll
        for (int r = 0; r < 4; ++r)
          if (nt * 16 + g * 4 + r > ql) sacc[nt][r] = -1e30f;
    }

    float m0 = -1e30f;
#pragma unroll
    for (int nt = 0; nt < 4; ++nt) {
      float a = fmaxf(fmaxf(sacc[nt][0], sacc[nt][1]), fmaxf(sacc[nt][2], sacc[nt][3]));
      m0 = fmaxf(m0, a);
    }
    m0 = fmaxf(m0, __shfl_xor(m0, 16));
    m0 = fmaxf(m0, __shfl_xor(m0, 32));

    if (__any(m0 > mrun + 32.0f)) {
      float mnew = fmaxf(mrun, m0);
      float corr = __builtin_amdgcn_exp2f(GAM * (mrun - mnew));
      lsum *= corr;
#pragma unroll
      for (int dt = 0; dt < 4; ++dt) yacc[dt] *= corr;
      mrun = mnew;
    }

    float bexp = -GAM * mrun;
    float psum = 0.f;
#pragma unroll
    for (int nt = 0; nt < 4; ++nt) {
      float p0 = __builtin_amdgcn_exp2f(fmaf(sacc[nt][0], GAM, bexp));
      float p1 = __builtin_amdgcn_exp2f(fmaf(sacc[nt][1], GAM, bexp));
      float p2 = __builtin_amdgcn_exp2f(fmaf(sacc[nt][2], GAM, bexp));
      float p3 = __builtin_amdgcn_exp2f(fmaf(sacc[nt][3], GAM, bexp));
      psum += (p0 + p1) + (p2 + p3);
      uint2v pkv;
      pkv[0] = pack_bf2(p0, p1);
      pkv[1] = pack_bf2(p2, p3);
      *(uint2v*)(pw + c * 72 + nt * 16 + g * 4) = pkv;
    }
    lsum += psum;

#pragma unroll
    for (int kk = 0; kk < 2; ++kk) {
      bf16x8 pb = *(const bf16x8*)(pw + c * 72 + kk * 32 + g * 8);
#pragma unroll
      for (int dt = 0; dt < 4; ++dt) {
        int n = dt * 16 + c;
        bf16x8 vf = *(const bf16x8*)(Vt + n * 64 + ((kk * 32 + g * 8) ^ ((n & 7) << 3)));
        yacc[dt] = MFMA16(vf, pb, yacc[dt]);
      }
    }
  }

  lsum += __shfl_xor(lsum, 16);
  lsum += __shfl_xor(lsum, 32);
  float inv = 1.0f / lsum;
  int row = q0 + w * 16 + c;
  unsigned short* yp = yb + ((size_t)(b * 2048 + row)) * 1024 + h * 64;
#pragma unroll
  for (int dt = 0; dt < 4; ++dt) {
    uint2v pkv;
    pkv[0] = pack_bf2(yacc[dt][0] * inv, yacc[dt][1] * inv);
    pkv[1] = pack_bf2(yacc[dt][2] * inv, yacc[dt][3] * inv);
    *(uint2v*)(yp + dt * 16 + g * 4) = pkv;
  }
}

// ---------------------------------------------------------------- launch
extern "C" void kernel_launch(void* const* d_in, const int* in_sizes, int n_in,
                              void* d_out, int out_size, void* d_ws, size_t ws_size,
                              hipStream_t stream) {
  const float* x     = (const float*)d_in[0];
  const float* wqkv  = (const float*)d_in[1];
  const float* wproj = (const float*)d_in[2];
  float* out = (float*)d_out;

  unsigned short* ws     = (unsigned short*)d_ws;
  unsigned short* xb     = ws;                       // 8388608
  unsigned short* wqkvb  = xb + 8388608;             // 3145728
  unsigned short* wprojb = wqkvb + 3145728;          // 1048576
  unsigned short* qkvb   = wprojb + 1048576;         // 3 * 8388608 (q,k,v)
  unsigned short* yb     = qkvb + 3 * 8388608;       // 8388608

  cvt3<<<2048, 256, 0, stream>>>(x, wqkv, wproj, xb, wqkvb, wprojb);

  // gemm1: BM=256 BN=128 BK=32, 3-ring 72KB LDS, grid 768
  gemmf<0, 8><<<768, 256, 73728, stream>>>(xb, wqkvb, qkvb, nullptr, 8192, 3072, 1024);
  attn_fwd<<<2048, 256, 0, stream>>>(qkvb, qkvb + 8388608, qkvb + 2 * 8388608, yb);
  // gemm2: BM=128 BN=128, 48KB LDS, grid 512
  gemmf<1, 4><<<512, 256, 49152, stream>>>(yb, wprojb, nullptr, out, 8192, 1024, 1024);
}